// Round 3
// baseline (137.634 us; speedup 1.0000x reference)
//
#include <hip/hip_runtime.h>
#include <math.h>

// Problem dims: B=64, S=T=128, D=1024, V=32000
// Output layout (fp32, concatenated):
//   src  @0          [64,128,1024]
//   satt @8388608    [64,128,1024]
//   at   @16777216   [64,128,128]
//   tgt  @17825792   [64,128,1024]
//   tatt @26214400   [64,128,1024]
//   ta   @34603008   [64,128,128]  (holds raw scores first)

#define NEG_INF -9999.0f

typedef __attribute__((ext_vector_type(8))) short   bf16x8;
typedef __attribute__((ext_vector_type(4))) float   f32x4;
typedef __attribute__((ext_vector_type(8))) unsigned short u16x8;

static __device__ inline ushort f2bf(float f) {
    union { float f; unsigned u; } v; v.f = f;
    unsigned r = v.u + 0x7fff + ((v.u >> 16) & 1);   // RNE
    return (ushort)(r >> 16);
}

// ---------------------------------------------------------------------------
// K1: fused embedding gather + avgpool3(SAME) + residual + bf16 row-major
//     copy (eb) + bf16 transposed copy (ebt).
// Block = (b, 128-wide d-chunk); grid = B*8; 256 threads.
// LDS tile sm[pos=128][d=128] (+pad 8): table slices read ONCE per (b,pos).
// ---------------------------------------------------------------------------
__global__ __launch_bounds__(256) void k_embed_all(
    const int* __restrict__ sent, const float* __restrict__ table,
    float* __restrict__ out, ushort* __restrict__ eb, ushort* __restrict__ ebt)
{
    __shared__ float sm[128][136];   // stride 136 floats (544B, 16B-aligned)
    int blk = blockIdx.x;
    int b = blk >> 3, d0 = (blk & 7) << 7;
    int tid = threadIdx.x;
    const int* ids = sent + b * 128;
    int pg = tid >> 5;               // 0..7 position sub-row
    int c4 = (tid & 31) << 2;        // 0..124 step 4 (d offset)

    // phase 1: gather raw table slices into LDS (each row slice read once)
#pragma unroll
    for (int pp = 0; pp < 16; ++pp) {
        int pos = (pp << 3) + pg;
        int id = ids[pos];
        float4 v = *(const float4*)(table + (size_t)id * 1024 + d0 + c4);
        *(float4*)&sm[pos][c4] = v;
    }
    __syncthreads();

    // phase 2: pool + residual; write fp32 out + bf16 eb; keep pooled in regs
    float4 oreg[16];
#pragma unroll
    for (int pp = 0; pp < 16; ++pp) {
        int pos = (pp << 3) + pg;
        float4 c = *(const float4*)&sm[pos][c4];
        float4 a = c;
        if (pos > 0) {
            float4 p = *(const float4*)&sm[pos - 1][c4];
            a.x += p.x; a.y += p.y; a.z += p.z; a.w += p.w;
        }
        if (pos < 127) {
            float4 n = *(const float4*)&sm[pos + 1][c4];
            a.x += n.x; a.y += n.y; a.z += n.z; a.w += n.w;
        }
        float inv = (pos == 0 || pos == 127) ? 0.5f : (1.0f / 3.0f);
        float4 o;
        o.x = fmaf(a.x, inv, c.x);
        o.y = fmaf(a.y, inv, c.y);
        o.z = fmaf(a.z, inv, c.z);
        o.w = fmaf(a.w, inv, c.w);
        oreg[pp] = o;
        size_t base = (size_t)b * 131072 + (size_t)pos * 1024 + d0 + c4;
        *(float4*)(out + base) = o;
        ushort4 h;
        h.x = f2bf(o.x); h.y = f2bf(o.y); h.z = f2bf(o.z); h.w = f2bf(o.w);
        *(ushort4*)(eb + base) = h;
    }
    __syncthreads();

    // phase 3a: store pooled values back into sm (in-place transpose source)
#pragma unroll
    for (int pp = 0; pp < 16; ++pp) {
        int pos = (pp << 3) + pg;
        *(float4*)&sm[pos][c4] = oreg[pp];
    }
    __syncthreads();

    // phase 3b: transposed bf16 write  ebt[b][d0+d][pos]
    int d = tid >> 1, half = tid & 1;
    ushort* dst = ebt + (size_t)b * 131072 + (size_t)(d0 + d) * 128 + (half << 6);
#pragma unroll
    for (int k = 0; k < 8; ++k) {
        u16x8 h;
#pragma unroll
        for (int j = 0; j < 8; ++j)
            h[j] = f2bf(sm[(half << 6) + (k << 3) + j][d]);
        *(u16x8*)(dst + (k << 3)) = h;
    }
}

// ---------------------------------------------------------------------------
// K2: raw scores via MFMA: mul[b,t,s] = dot(tgt_bf16[t,:], src_bf16[s,:])
// 1-wave blocks, 32x32 tile; grid = B*16 (4x4 tiles). K=1024.
// ---------------------------------------------------------------------------
__global__ __launch_bounds__(64) void k_scores_mfma(
    const ushort* __restrict__ ebS, const ushort* __restrict__ ebT,
    float* __restrict__ mul)
{
    int blk = blockIdx.x;             // b*16 + (tt*4 + st)
    int b = blk >> 4;
    int t0 = ((blk >> 2) & 3) * 32, s0 = (blk & 3) * 32;
    int l = threadIdx.x;
    int rA = l & 15, kg = (l >> 4) << 3;
    const ushort* ap = ebT + (size_t)b * 131072 + (size_t)(t0 + rA) * 1024 + kg;
    const ushort* bp = ebS + (size_t)b * 131072 + (size_t)(s0 + rA) * 1024 + kg;
    f32x4 acc[2][2] = {};
#pragma unroll 4
    for (int k0 = 0; k0 < 1024; k0 += 32) {
        bf16x8 af[2], bf[2];
#pragma unroll
        for (int i = 0; i < 2; ++i) {
            af[i] = *(const bf16x8*)(ap + (size_t)(i << 4) * 1024 + k0);
            bf[i] = *(const bf16x8*)(bp + (size_t)(i << 4) * 1024 + k0);
        }
#pragma unroll
        for (int i = 0; i < 2; ++i)
#pragma unroll
            for (int j = 0; j < 2; ++j)
                acc[i][j] = __builtin_amdgcn_mfma_f32_16x16x32_bf16(
                    af[i], bf[j], acc[i][j], 0, 0, 0);
    }
    float* mb = mul + (size_t)b * 16384;
    int cn = l & 15, rq = (l >> 4) << 2;
#pragma unroll
    for (int i = 0; i < 2; ++i)
#pragma unroll
        for (int j = 0; j < 2; ++j)
#pragma unroll
            for (int r = 0; r < 4; ++r)
                mb[(size_t)(t0 + (i << 4) + rq + r) * 128 + s0 + (j << 4) + cn]
                    = acc[i][j][r];
}

// ---------------------------------------------------------------------------
// K3: fused dual softmax. One block per b (256 thr); mul[b] staged in LDS
// (pad 129 -> conflict-free row AND column reads).
//   ta[b,t,s] = softmax_s(masked mul)   (+ pta bf16)
//   at[b,s,t] = softmax_t(masked mul^T) (+ pat bf16)
// ---------------------------------------------------------------------------
__global__ __launch_bounds__(256) void k_softmax_both(
    const float* __restrict__ mul, const int* __restrict__ ssent,
    const int* __restrict__ tsent, float* __restrict__ at,
    float* __restrict__ ta, ushort* __restrict__ pat, ushort* __restrict__ pta)
{
    __shared__ float sm[128][129];
    int b = blockIdx.x;
    int tid = threadIdx.x;
    const float* mb = mul + (size_t)b * 16384;
#pragma unroll
    for (int pp = 0; pp < 16; ++pp) {
        int f = (pp << 8) + tid;             // float4 index 0..4095
        int row = f >> 5, c4 = (f & 31) << 2;
        float4 v = *(const float4*)(mb + ((size_t)f << 2));
        sm[row][c4] = v.x; sm[row][c4 + 1] = v.y;
        sm[row][c4 + 2] = v.z; sm[row][c4 + 3] = v.w;
    }
    __syncthreads();
    int w = tid >> 6, lane = tid & 63;
    bool sv0 = ssent[b * 128 + lane] > 0;
    bool sv1 = ssent[b * 128 + lane + 64] > 0;
    bool tv0 = tsent[b * 128 + lane] > 0;
    bool tv1 = tsent[b * 128 + lane + 64] > 0;

    // row softmax over s -> ta [B][T][S]
    for (int i = 0; i < 32; ++i) {
        int t = (w << 5) + i;
        bool tm = tsent[b * 128 + t] > 0;
        float v0 = (tm && sv0) ? sm[t][lane] : NEG_INF;
        float v1 = (tm && sv1) ? sm[t][lane + 64] : NEG_INF;
        float m = fmaxf(v0, v1);
#pragma unroll
        for (int off = 32; off; off >>= 1) m = fmaxf(m, __shfl_xor(m, off));
        float e0 = __expf(v0 - m), e1 = __expf(v1 - m);
        float sum = e0 + e1;
#pragma unroll
        for (int off = 32; off; off >>= 1) sum += __shfl_xor(sum, off);
        float r = 1.0f / sum;
        float p0 = e0 * r, p1 = e1 * r;
        size_t o = (size_t)(b * 128 + t) * 128;
        ta[o + lane] = p0; ta[o + lane + 64] = p1;
        pta[o + lane] = f2bf(p0); pta[o + lane + 64] = f2bf(p1);
    }
    // column softmax over t -> at [B][S][T]
    for (int i = 0; i < 32; ++i) {
        int s = (w << 5) + i;
        bool smk = ssent[b * 128 + s] > 0;
        float v0 = (smk && tv0) ? sm[lane][s] : NEG_INF;
        float v1 = (smk && tv1) ? sm[lane + 64][s] : NEG_INF;
        float m = fmaxf(v0, v1);
#pragma unroll
        for (int off = 32; off; off >>= 1) m = fmaxf(m, __shfl_xor(m, off));
        float e0 = __expf(v0 - m), e1 = __expf(v1 - m);
        float sum = e0 + e1;
#pragma unroll
        for (int off = 32; off; off >>= 1) sum += __shfl_xor(sum, off);
        float r = 1.0f / sum;
        float p0 = e0 * r, p1 = e1 * r;
        size_t o = (size_t)(b * 128 + s) * 128;
        at[o + lane] = p0; at[o + lane + 64] = p1;
        pat[o + lane] = f2bf(p0); pat[o + lane + 64] = f2bf(p1);
    }
}

// ---------------------------------------------------------------------------
// K4: attention matmul via MFMA: C[b,r,d] = sum_k P[b,r,k] * Ebt[b,d,k]
// 1-wave blocks, 64x64 tile; grid = B*32 (2 r-tiles x 16 d-tiles). K=128.
// ---------------------------------------------------------------------------
__global__ __launch_bounds__(64) void k_attmm_mfma(
    const ushort* __restrict__ P, const ushort* __restrict__ Ebt,
    float* __restrict__ C)
{
    int blk = blockIdx.x;             // b*32 + (rt*16 + dt)
    int b = blk >> 5;
    int r0 = ((blk >> 4) & 1) * 64;
    int d0 = (blk & 15) * 64;
    int l = threadIdx.x;
    int rA = l & 15, kg = (l >> 4) << 3;
    const ushort* Pb = P   + (size_t)b * 16384  + (size_t)(r0 + rA) * 128 + kg;
    const ushort* Eb = Ebt + (size_t)b * 131072 + (size_t)(d0 + rA) * 128 + kg;
    f32x4 acc[4][4] = {};
#pragma unroll
    for (int k0 = 0; k0 < 128; k0 += 32) {
        bf16x8 af[4], bf[4];
#pragma unroll
        for (int i = 0; i < 4; ++i) {
            af[i] = *(const bf16x8*)(Pb + (i << 4) * 128 + k0);
            bf[i] = *(const bf16x8*)(Eb + (i << 4) * 128 + k0);
        }
#pragma unroll
        for (int i = 0; i < 4; ++i)
#pragma unroll
            for (int j = 0; j < 4; ++j)
                acc[i][j] = __builtin_amdgcn_mfma_f32_16x16x32_bf16(
                    af[i], bf[j], acc[i][j], 0, 0, 0);
    }
    float* Cb = C + (size_t)b * 131072;
    int cn = l & 15, rq = (l >> 4) << 2;
#pragma unroll
    for (int i = 0; i < 4; ++i)
#pragma unroll
        for (int j = 0; j < 4; ++j)
#pragma unroll
            for (int r = 0; r < 4; ++r)
                Cb[(size_t)(r0 + (i << 4) + rq + r) * 1024 + d0 + (j << 4) + cn]
                    = acc[i][j][r];
}

// ======================= fp32 fallback kernels (ws too small) ==============
__global__ __launch_bounds__(256) void k_embed_pool(
    const int* __restrict__ sent, const float* __restrict__ table,
    float* __restrict__ out)
{
    int blk = blockIdx.x;
    int b = blk >> 7, pos = blk & 127;
    const int* ids = sent + b * 128;
    int idc = ids[pos];
    int idp = (pos > 0)   ? ids[pos - 1] : -1;
    int idn = (pos < 127) ? ids[pos + 1] : -1;
    float inv = (pos == 0 || pos == 127) ? 0.5f : (1.0f / 3.0f);
    int d4 = threadIdx.x;
    float4 c = ((const float4*)(table + (size_t)idc * 1024))[d4];
    float4 a = c;
    if (idp >= 0) {
        float4 p = ((const float4*)(table + (size_t)idp * 1024))[d4];
        a.x += p.x; a.y += p.y; a.z += p.z; a.w += p.w;
    }
    if (idn >= 0) {
        float4 n = ((const float4*)(table + (size_t)idn * 1024))[d4];
        a.x += n.x; a.y += n.y; a.z += n.z; a.w += n.w;
    }
    float4 o;
    o.x = fmaf(a.x, inv, c.x); o.y = fmaf(a.y, inv, c.y);
    o.z = fmaf(a.z, inv, c.z); o.w = fmaf(a.w, inv, c.w);
    ((float4*)(out + (size_t)blk * 1024))[d4] = o;
}

__global__ __launch_bounds__(256) void k_scores(
    const float* __restrict__ srcE, const float* __restrict__ tgtE,
    float* __restrict__ mul)
{
    __shared__ float At[32][68];
    __shared__ float Bs[32][68];
    int b = blockIdx.y;
    int t0 = (blockIdx.x >> 1) * 64, s0 = (blockIdx.x & 1) * 64;
    const float* tg = tgtE + (size_t)b * 131072;
    const float* sr = srcE + (size_t)b * 131072;
    int tid = threadIdx.x, ty = tid >> 4, tx = tid & 15;
    float acc[4][4] = {};
    for (int k0 = 0; k0 < 1024; k0 += 32) {
        for (int q = tid; q < 512; q += 256) {
            int r = q >> 3, kc = (q & 7) << 2;
            float4 v = *(const float4*)(tg + (size_t)(t0 + r) * 1024 + k0 + kc);
            At[kc+0][r] = v.x; At[kc+1][r] = v.y; At[kc+2][r] = v.z; At[kc+3][r] = v.w;
            float4 w2 = *(const float4*)(sr + (size_t)(s0 + r) * 1024 + k0 + kc);
            Bs[kc+0][r] = w2.x; Bs[kc+1][r] = w2.y; Bs[kc+2][r] = w2.z; Bs[kc+3][r] = w2.w;
        }
        __syncthreads();
#pragma unroll 8
        for (int kk = 0; kk < 32; ++kk) {
            float4 av = *(const float4*)&At[kk][ty << 2];
            float4 bv = *(const float4*)&Bs[kk][tx << 2];
            float aa[4] = {av.x, av.y, av.z, av.w};
            float bb[4] = {bv.x, bv.y, bv.z, bv.w};
#pragma unroll
            for (int i = 0; i < 4; ++i)
#pragma unroll
                for (int j = 0; j < 4; ++j)
                    acc[i][j] = fmaf(aa[i], bb[j], acc[i][j]);
        }
        __syncthreads();
    }
    float* mb = mul + (size_t)b * 16384;
#pragma unroll
    for (int i = 0; i < 4; ++i)
        *(float4*)(mb + (size_t)(t0 + (ty << 2) + i) * 128 + s0 + (tx << 2)) =
            make_float4(acc[i][0], acc[i][1], acc[i][2], acc[i][3]);
}

__global__ __launch_bounds__(64) void k_softmax_at(
    const float* __restrict__ mul, const int* __restrict__ ssent,
    const int* __restrict__ tsent, float* __restrict__ at)
{
    int blk = blockIdx.x;
    int b = blk >> 7, s = blk & 127;
    int lane = threadIdx.x;
    bool smk = ssent[b * 128 + s] > 0;
    const float* mb = mul + (size_t)b * 16384;
    int t0 = lane, t1 = lane + 64;
    float v0 = (smk && tsent[b * 128 + t0] > 0) ? mb[(size_t)t0 * 128 + s] : NEG_INF;
    float v1 = (smk && tsent[b * 128 + t1] > 0) ? mb[(size_t)t1 * 128 + s] : NEG_INF;
    float m = fmaxf(v0, v1);
#pragma unroll
    for (int off = 32; off; off >>= 1) m = fmaxf(m, __shfl_xor(m, off));
    float e0 = __expf(v0 - m), e1 = __expf(v1 - m);
    float sum = e0 + e1;
#pragma unroll
    for (int off = 32; off; off >>= 1) sum += __shfl_xor(sum, off);
    float r = 1.0f / sum;
    float* ab = at + (size_t)blk * 128;
    ab[t0] = e0 * r; ab[t1] = e1 * r;
}

__global__ __launch_bounds__(64) void k_softmax_ta(
    float* __restrict__ mul, const int* __restrict__ ssent,
    const int* __restrict__ tsent)
{
    int blk = blockIdx.x;
    int b = blk >> 7, t = blk & 127;
    int lane = threadIdx.x;
    bool tm = tsent[b * 128 + t] > 0;
    float* mb = mul + (size_t)blk * 128;
    int s0 = lane, s1 = lane + 64;
    float v0 = (tm && ssent[b * 128 + s0] > 0) ? mb[s0] : NEG_INF;
    float v1 = (tm && ssent[b * 128 + s1] > 0) ? mb[s1] : NEG_INF;
    float m = fmaxf(v0, v1);
#pragma unroll
    for (int off = 32; off; off >>= 1) m = fmaxf(m, __shfl_xor(m, off));
    float e0 = __expf(v0 - m), e1 = __expf(v1 - m);
    float sum = e0 + e1;
#pragma unroll
    for (int off = 32; off; off >>= 1) sum += __shfl_xor(sum, off);
    float r = 1.0f / sum;
    mb[s0] = e0 * r; mb[s1] = e1 * r;
}

__global__ __launch_bounds__(256) void k_attmm(
    const float* __restrict__ P, const float* __restrict__ E,
    float* __restrict__ C)
{
    __shared__ float Pt[32][68];
    __shared__ float Et[32][68];
    int b = blockIdx.y;
    int r0 = (blockIdx.x >> 4) * 64, d0 = (blockIdx.x & 15) * 64;
    const float* Pb = P + (size_t)b * 16384;
    const float* Eb = E + (size_t)b * 131072;
    float* Cb = C + (size_t)b * 131072;
    int tid = threadIdx.x, ty = tid >> 4, tx = tid & 15;
    float acc[4][4] = {};
    for (int k0 = 0; k0 < 128; k0 += 32) {
        for (int q = tid; q < 512; q += 256) {
            int r = q >> 3, kc = (q & 7) << 2;
            float4 v = *(const float4*)(Pb + (size_t)(r0 + r) * 128 + k0 + kc);
            Pt[kc+0][r] = v.x; Pt[kc+1][r] = v.y; Pt[kc+2][r] = v.z; Pt[kc+3][r] = v.w;
            int kr = q >> 4, dc = (q & 15) << 2;
            *(float4*)&Et[kr][dc] = *(const float4*)(Eb + (size_t)(k0 + kr) * 1024 + d0 + dc);
        }
        __syncthreads();
#pragma unroll 8
        for (int kk = 0; kk < 32; ++kk) {
            float4 av = *(const float4*)&Pt[kk][ty << 2];
            float4 bv = *(const float4*)&Et[kk][tx << 2];
            float aa[4] = {av.x, av.y, av.z, av.w};
            float bb[4] = {bv.x, bv.y, bv.z, bv.w};
#pragma unroll
            for (int i = 0; i < 4; ++i)
#pragma unroll
                for (int j = 0; j < 4; ++j)
                    acc[i][j] = fmaf(aa[i], bb[j], acc[i][j]);
        }
        __syncthreads();
    }
#pragma unroll
    for (int i = 0; i < 4; ++i)
        *(float4*)(Cb + (size_t)(r0 + (ty << 2) + i) * 1024 + d0 + (tx << 2)) =
            make_float4(acc[i][0], acc[i][1], acc[i][2], acc[i][3]);
}

// ---------------------------------------------------------------------------
extern "C" void kernel_launch(void* const* d_in, const int* in_sizes, int n_in,
                              void* d_out, int out_size, void* d_ws, size_t ws_size,
                              hipStream_t stream)
{
    const int*   ssent = (const int*)d_in[0];
    const int*   tsent = (const int*)d_in[1];
    const float* stab  = (const float*)d_in[4];
    const float* ttab  = (const float*)d_in[5];
    float* out  = (float*)d_out;

    float* src  = out + 0;
    float* satt = out + 8388608;
    float* at   = out + 16777216;
    float* tgt  = out + 17825792;
    float* tatt = out + 26214400;
    float* ta   = out + 34603008;

    // ws layout (bf16): Eb_src, Eb_tgt [B][128][1024]; Ebt_src, Ebt_tgt
    // [B][1024][128]; Pta [B][T][S]; Pat [B][S][T]
    const size_t EB_ELEMS = 8388608;     // 64*128*1024
    const size_t P_ELEMS  = 1048576;     // 64*128*128
    const size_t WS_NEED  = (4 * EB_ELEMS + 2 * P_ELEMS) * sizeof(ushort); // 75.5MB

    if (ws_size >= WS_NEED) {
        ushort* ebS  = (ushort*)d_ws;
        ushort* ebT  = ebS  + EB_ELEMS;
        ushort* ebtS = ebT  + EB_ELEMS;
        ushort* ebtT = ebtS + EB_ELEMS;
        ushort* pta  = ebtT + EB_ELEMS;
        ushort* pat  = pta  + P_ELEMS;

        k_embed_all<<<512, 256, 0, stream>>>(ssent, stab, src, ebS, ebtS);
        k_embed_all<<<512, 256, 0, stream>>>(tsent, ttab, tgt, ebT, ebtT);

        k_scores_mfma<<<1024, 64, 0, stream>>>(ebS, ebT, ta);

        k_softmax_both<<<64, 256, 0, stream>>>(ta, ssent, tsent, at, ta, pat, pta);

        k_attmm_mfma<<<2048, 64, 0, stream>>>(pta, ebtS, satt);
        k_attmm_mfma<<<2048, 64, 0, stream>>>(pat, ebtT, tatt);
    } else {
        // fp32 fallback
        k_embed_pool<<<8192, 256, 0, stream>>>(ssent, stab, src);
        k_embed_pool<<<8192, 256, 0, stream>>>(tsent, ttab, tgt);
        k_scores<<<dim3(4, 64), 256, 0, stream>>>(src, tgt, ta);
        k_softmax_at<<<8192, 64, 0, stream>>>(ta, ssent, tsent, at);
        k_softmax_ta<<<8192, 64, 0, stream>>>(ta, ssent, tsent);
        k_attmm<<<dim3(32, 64), 256, 0, stream>>>(ta, src, satt);
        k_attmm<<<dim3(32, 64), 256, 0, stream>>>(at, tgt, tatt);
    }
}

// Round 4
// 102.736 us; speedup vs baseline: 1.3397x; 1.3397x over previous
//
#include <hip/hip_runtime.h>
#include <math.h>

// Problem dims: B=64, S=T=128, D=1024, V=32000
// Output layout (fp32, concatenated):
//   src  @0          [64,128,1024]
//   satt @8388608    [64,128,1024]
//   at   @16777216   [64,128,128]
//   tgt  @17825792   [64,128,1024]
//   tatt @26214400   [64,128,1024]
//   ta   @34603008   [64,128,128]

#define NEG_INF -9999.0f

typedef __attribute__((ext_vector_type(8))) short   bf16x8;
typedef __attribute__((ext_vector_type(4))) float   f32x4;
typedef __attribute__((ext_vector_type(8))) unsigned short u16x8;

static __device__ inline ushort f2bf(float f) {
    union { float f; unsigned u; } v; v.f = f;
    unsigned r = v.u + 0x7fff + ((v.u >> 16) & 1);   // RNE
    return (ushort)(r >> 16);
}

// ---------------------------------------------------------------------------
// K1: fused embedding gather + avgpool3 + residual + bf16 row copy + bf16
//     transposed copy, BOTH sides in one launch. Grid 1024 (side = blk>>9).
// ---------------------------------------------------------------------------
__global__ __launch_bounds__(256) void k_embed_all2(
    const int* __restrict__ ssent, const int* __restrict__ tsent,
    const float* __restrict__ stab, const float* __restrict__ ttab,
    float* __restrict__ srcO, float* __restrict__ tgtO,
    ushort* __restrict__ ebS, ushort* __restrict__ ebT,
    ushort* __restrict__ ebtS, ushort* __restrict__ ebtT)
{
    __shared__ float sm[128][136];          // 68 KB; reused as ushort in ph3
    ushort* smh = (ushort*)&sm[0][0];       // stride 272 ushorts per pos
    int blk = blockIdx.x;
    int side = blk >> 9;
    int rem = blk & 511;
    int b = rem >> 3, d0 = (rem & 7) << 7;
    const int*   sent  = side ? tsent : ssent;
    const float* table = side ? ttab  : stab;
    float*  out = side ? tgtO : srcO;
    ushort* eb  = side ? ebT  : ebS;
    ushort* ebt = side ? ebtT : ebtS;

    int tid = threadIdx.x;
    const int* ids = sent + b * 128;
    int pg = tid >> 5;                       // 0..7
    int c4 = (tid & 31) << 2;                // 0..124

    int myids[16];
#pragma unroll
    for (int pp = 0; pp < 16; ++pp) myids[pp] = ids[(pp << 3) + pg];

    // phase 1: gather raw table slices (each slice read once)
#pragma unroll
    for (int pp = 0; pp < 16; ++pp) {
        int pos = (pp << 3) + pg;
        float4 v = *(const float4*)(table + (size_t)myids[pp] * 1024 + d0 + c4);
        *(float4*)&sm[pos][c4] = v;
    }
    __syncthreads();

    // phase 2: pool + residual; write fp32 out + bf16 eb; keep bf16 in regs
    ushort4 hreg[16];
#pragma unroll
    for (int pp = 0; pp < 16; ++pp) {
        int pos = (pp << 3) + pg;
        float4 c = *(const float4*)&sm[pos][c4];
        float4 a = c;
        if (pos > 0) {
            float4 p = *(const float4*)&sm[pos - 1][c4];
            a.x += p.x; a.y += p.y; a.z += p.z; a.w += p.w;
        }
        if (pos < 127) {
            float4 n = *(const float4*)&sm[pos + 1][c4];
            a.x += n.x; a.y += n.y; a.z += n.z; a.w += n.w;
        }
        float inv = (pos == 0 || pos == 127) ? 0.5f : (1.0f / 3.0f);
        float4 o;
        o.x = fmaf(a.x, inv, c.x); o.y = fmaf(a.y, inv, c.y);
        o.z = fmaf(a.z, inv, c.z); o.w = fmaf(a.w, inv, c.w);
        size_t base = (size_t)b * 131072 + (size_t)pos * 1024 + d0 + c4;
        *(float4*)(out + base) = o;
        ushort4 h;
        h.x = f2bf(o.x); h.y = f2bf(o.y); h.z = f2bf(o.z); h.w = f2bf(o.w);
        *(ushort4*)(eb + base) = h;
        hreg[pp] = h;
    }
    __syncthreads();

    // phase 3a: stage bf16 values into LDS (ushort view)
#pragma unroll
    for (int pp = 0; pp < 16; ++pp) {
        int pos = (pp << 3) + pg;
        *(ushort4*)(smh + pos * 272 + c4) = hreg[pp];
    }
    __syncthreads();

    // phase 3b: transposed write  ebt[b][d0+d][pos]
    int d = tid >> 1, half = tid & 1;
    ushort* dst = ebt + (size_t)b * 131072 + (size_t)(d0 + d) * 128 + (half << 6);
#pragma unroll
    for (int k = 0; k < 8; ++k) {
        u16x8 h;
#pragma unroll
        for (int j = 0; j < 8; ++j)
            h[j] = smh[(size_t)((half << 6) + (k << 3) + j) * 272 + d];
        *(u16x8*)(dst + (k << 3)) = h;
    }
}

// ---------------------------------------------------------------------------
// K2: scores via MFMA, split-K x4: 4 waves/block, each K=256, LDS reduce.
// 32x32 tile; grid = B*16. Writes raw scores to ws scratch (mulraw).
// ---------------------------------------------------------------------------
__global__ __launch_bounds__(256) void k_scores_splitk(
    const ushort* __restrict__ ebS, const ushort* __restrict__ ebT,
    float* __restrict__ mul)
{
    __shared__ float red[3][64][17];
    int blk = blockIdx.x;
    int b = blk >> 4;
    int t0 = ((blk >> 2) & 3) * 32, s0 = (blk & 3) * 32;
    int tid = threadIdx.x;
    int w = tid >> 6, l = tid & 63;
    int rA = l & 15, kg = (l >> 4) << 3;
    int kbase = w << 8;                       // 0,256,512,768
    const ushort* ap = ebT + (size_t)b * 131072 + (size_t)(t0 + rA) * 1024 + kbase + kg;
    const ushort* bp = ebS + (size_t)b * 131072 + (size_t)(s0 + rA) * 1024 + kbase + kg;
    f32x4 acc[2][2] = {};
#pragma unroll 4
    for (int k0 = 0; k0 < 256; k0 += 32) {
        bf16x8 af[2], bf[2];
#pragma unroll
        for (int i = 0; i < 2; ++i) {
            af[i] = *(const bf16x8*)(ap + (size_t)(i << 4) * 1024 + k0);
            bf[i] = *(const bf16x8*)(bp + (size_t)(i << 4) * 1024 + k0);
        }
#pragma unroll
        for (int i = 0; i < 2; ++i)
#pragma unroll
            for (int j = 0; j < 2; ++j)
                acc[i][j] = __builtin_amdgcn_mfma_f32_16x16x32_bf16(
                    af[i], bf[j], acc[i][j], 0, 0, 0);
    }
    if (w > 0) {
#pragma unroll
        for (int i = 0; i < 2; ++i)
#pragma unroll
            for (int j = 0; j < 2; ++j)
#pragma unroll
                for (int r = 0; r < 4; ++r)
                    red[w - 1][l][((i << 1) + j) * 4 + r] = acc[i][j][r];
    }
    __syncthreads();
    if (w == 0) {
#pragma unroll
        for (int i = 0; i < 2; ++i)
#pragma unroll
            for (int j = 0; j < 2; ++j)
#pragma unroll
                for (int r = 0; r < 4; ++r) {
                    int idx = ((i << 1) + j) * 4 + r;
                    acc[i][j][r] += red[0][l][idx] + red[1][l][idx] + red[2][l][idx];
                }
        float* mb = mul + (size_t)b * 16384;
        int cn = l & 15, rq = (l >> 4) << 2;
#pragma unroll
        for (int i = 0; i < 2; ++i)
#pragma unroll
            for (int j = 0; j < 2; ++j)
#pragma unroll
                for (int r = 0; r < 4; ++r)
                    mb[(size_t)(t0 + (i << 4) + rq + r) * 128 + s0 + (j << 4) + cn]
                        = acc[i][j][r];
    }
}

// ---------------------------------------------------------------------------
// K3: dual softmax, full occupancy. Block (b,i): row t=i (over s) AND
// column s=i (over t). 8192 blocks x 64 thr. Reads scratch, writes ta/at
// fp32 + pta/pat bf16.
// ---------------------------------------------------------------------------
__global__ __launch_bounds__(64) void k_softmax_dual(
    const float* __restrict__ mul, const int* __restrict__ ssent,
    const int* __restrict__ tsent, float* __restrict__ at,
    float* __restrict__ ta, ushort* __restrict__ pat, ushort* __restrict__ pta)
{
    int blk = blockIdx.x;                    // b*128 + i
    int b = blk >> 7, i = blk & 127;
    int lane = threadIdx.x;
    const float* mb = mul + (size_t)b * 16384;
    bool sv0 = ssent[b * 128 + lane] > 0, sv1 = ssent[b * 128 + lane + 64] > 0;
    bool tv0 = tsent[b * 128 + lane] > 0, tv1 = tsent[b * 128 + lane + 64] > 0;

    // row softmax: t=i over s  -> ta[b,i,:]
    {
        bool tm = tsent[b * 128 + i] > 0;
        float v0 = (tm && sv0) ? mb[i * 128 + lane] : NEG_INF;
        float v1 = (tm && sv1) ? mb[i * 128 + lane + 64] : NEG_INF;
        float m = fmaxf(v0, v1);
#pragma unroll
        for (int off = 32; off; off >>= 1) m = fmaxf(m, __shfl_xor(m, off));
        float e0 = __expf(v0 - m), e1 = __expf(v1 - m);
        float sum = e0 + e1;
#pragma unroll
        for (int off = 32; off; off >>= 1) sum += __shfl_xor(sum, off);
        float r = 1.0f / sum;
        float p0 = e0 * r, p1 = e1 * r;
        size_t o = (size_t)blk * 128;
        ta[o + lane] = p0; ta[o + lane + 64] = p1;
        pta[o + lane] = f2bf(p0); pta[o + lane + 64] = f2bf(p1);
    }
    // column softmax: s=i over t -> at[b,i,:]
    {
        bool smk = ssent[b * 128 + i] > 0;
        float v0 = (smk && tv0) ? mb[lane * 128 + i] : NEG_INF;
        float v1 = (smk && tv1) ? mb[(lane + 64) * 128 + i] : NEG_INF;
        float m = fmaxf(v0, v1);
#pragma unroll
        for (int off = 32; off; off >>= 1) m = fmaxf(m, __shfl_xor(m, off));
        float e0 = __expf(v0 - m), e1 = __expf(v1 - m);
        float sum = e0 + e1;
#pragma unroll
        for (int off = 32; off; off >>= 1) sum += __shfl_xor(sum, off);
        float r = 1.0f / sum;
        float p0 = e0 * r, p1 = e1 * r;
        size_t o = (size_t)blk * 128;
        at[o + lane] = p0; at[o + lane + 64] = p1;
        pat[o + lane] = f2bf(p0); pat[o + lane + 64] = f2bf(p1);
    }
}

// ---------------------------------------------------------------------------
// K4: both attention matmuls, one launch. 64(r) x 32(d) tile, 1 wave;
// grid = 2*4096 = 8192. C[b,r,d] = sum_k P[b,r,k] * Ebt[b,d,k].
// ---------------------------------------------------------------------------
__global__ __launch_bounds__(64) void k_attmm2(
    const ushort* __restrict__ pta, const ushort* __restrict__ ebtS,
    float* __restrict__ satt,
    const ushort* __restrict__ pat, const ushort* __restrict__ ebtT,
    float* __restrict__ tatt)
{
    int blk = blockIdx.x;
    int q = blk >> 12;
    int rem = blk & 4095;                    // b*64 + rt*32 + dt
    int b = rem >> 6;
    int rt = (rem >> 5) & 1, dt = rem & 31;
    const ushort* P = q ? pat : pta;
    const ushort* E = q ? ebtT : ebtS;
    float* C = q ? tatt : satt;
    int r0 = rt << 6, d0 = dt << 5;
    int l = threadIdx.x;
    int rA = l & 15, kg = (l >> 4) << 3;
    const ushort* Pb = P + (size_t)b * 16384  + (size_t)(r0 + rA) * 128 + kg;
    const ushort* Eb = E + (size_t)b * 131072 + (size_t)(d0 + rA) * 128 + kg;
    f32x4 acc[4][2] = {};
#pragma unroll
    for (int k0 = 0; k0 < 128; k0 += 32) {
        bf16x8 af[4], bf[2];
#pragma unroll
        for (int i = 0; i < 4; ++i)
            af[i] = *(const bf16x8*)(Pb + (i << 4) * 128 + k0);
#pragma unroll
        for (int j = 0; j < 2; ++j)
            bf[j] = *(const bf16x8*)(Eb + (j << 4) * 128 + k0);
#pragma unroll
        for (int i = 0; i < 4; ++i)
#pragma unroll
            for (int j = 0; j < 2; ++j)
                acc[i][j] = __builtin_amdgcn_mfma_f32_16x16x32_bf16(
                    af[i], bf[j], acc[i][j], 0, 0, 0);
    }
    float* Cb = C + (size_t)b * 131072;
    int cn = l & 15, rq = (l >> 4) << 2;
#pragma unroll
    for (int i = 0; i < 4; ++i)
#pragma unroll
        for (int j = 0; j < 2; ++j)
#pragma unroll
            for (int r = 0; r < 4; ++r)
                Cb[(size_t)(r0 + (i << 4) + rq + r) * 1024 + d0 + (j << 4) + cn]
                    = acc[i][j][r];
}

// ======================= fp32 fallback kernels (ws too small) ==============
__global__ __launch_bounds__(256) void k_embed_pool(
    const int* __restrict__ sent, const float* __restrict__ table,
    float* __restrict__ out)
{
    int blk = blockIdx.x;
    int b = blk >> 7, pos = blk & 127;
    const int* ids = sent + b * 128;
    int idc = ids[pos];
    int idp = (pos > 0)   ? ids[pos - 1] : -1;
    int idn = (pos < 127) ? ids[pos + 1] : -1;
    float inv = (pos == 0 || pos == 127) ? 0.5f : (1.0f / 3.0f);
    int d4 = threadIdx.x;
    float4 c = ((const float4*)(table + (size_t)idc * 1024))[d4];
    float4 a = c;
    if (idp >= 0) {
        float4 p = ((const float4*)(table + (size_t)idp * 1024))[d4];
        a.x += p.x; a.y += p.y; a.z += p.z; a.w += p.w;
    }
    if (idn >= 0) {
        float4 n = ((const float4*)(table + (size_t)idn * 1024))[d4];
        a.x += n.x; a.y += n.y; a.z += n.z; a.w += n.w;
    }
    float4 o;
    o.x = fmaf(a.x, inv, c.x); o.y = fmaf(a.y, inv, c.y);
    o.z = fmaf(a.z, inv, c.z); o.w = fmaf(a.w, inv, c.w);
    ((float4*)(out + (size_t)blk * 1024))[d4] = o;
}

__global__ __launch_bounds__(256) void k_scores(
    const float* __restrict__ srcE, const float* __restrict__ tgtE,
    float* __restrict__ mul)
{
    __shared__ float At[32][68];
    __shared__ float Bs[32][68];
    int b = blockIdx.y;
    int t0 = (blockIdx.x >> 1) * 64, s0 = (blockIdx.x & 1) * 64;
    const float* tg = tgtE + (size_t)b * 131072;
    const float* sr = srcE + (size_t)b * 131072;
    int tid = threadIdx.x, ty = tid >> 4, tx = tid & 15;
    float acc[4][4] = {};
    for (int k0 = 0; k0 < 1024; k0 += 32) {
        for (int q = tid; q < 512; q += 256) {
            int r = q >> 3, kc = (q & 7) << 2;
            float4 v = *(const float4*)(tg + (size_t)(t0 + r) * 1024 + k0 + kc);
            At[kc+0][r] = v.x; At[kc+1][r] = v.y; At[kc+2][r] = v.z; At[kc+3][r] = v.w;
            float4 w2 = *(const float4*)(sr + (size_t)(s0 + r) * 1024 + k0 + kc);
            Bs[kc+0][r] = w2.x; Bs[kc+1][r] = w2.y; Bs[kc+2][r] = w2.z; Bs[kc+3][r] = w2.w;
        }
        __syncthreads();
#pragma unroll 8
        for (int kk = 0; kk < 32; ++kk) {
            float4 av = *(const float4*)&At[kk][ty << 2];
            float4 bv = *(const float4*)&Bs[kk][tx << 2];
            float aa[4] = {av.x, av.y, av.z, av.w};
            float bb[4] = {bv.x, bv.y, bv.z, bv.w};
#pragma unroll
            for (int i = 0; i < 4; ++i)
#pragma unroll
                for (int j = 0; j < 4; ++j)
                    acc[i][j] = fmaf(aa[i], bb[j], acc[i][j]);
        }
        __syncthreads();
    }
    float* mb = mul + (size_t)b * 16384;
#pragma unroll
    for (int i = 0; i < 4; ++i)
        *(float4*)(mb + (size_t)(t0 + (ty << 2) + i) * 128 + s0 + (tx << 2)) =
            make_float4(acc[i][0], acc[i][1], acc[i][2], acc[i][3]);
}

__global__ __launch_bounds__(64) void k_softmax_at(
    const float* __restrict__ mul, const int* __restrict__ ssent,
    const int* __restrict__ tsent, float* __restrict__ at)
{
    int blk = blockIdx.x;
    int b = blk >> 7, s = blk & 127;
    int lane = threadIdx.x;
    bool smk = ssent[b * 128 + s] > 0;
    const float* mb = mul + (size_t)b * 16384;
    int t0 = lane, t1 = lane + 64;
    float v0 = (smk && tsent[b * 128 + t0] > 0) ? mb[(size_t)t0 * 128 + s] : NEG_INF;
    float v1 = (smk && tsent[b * 128 + t1] > 0) ? mb[(size_t)t1 * 128 + s] : NEG_INF;
    float m = fmaxf(v0, v1);
#pragma unroll
    for (int off = 32; off; off >>= 1) m = fmaxf(m, __shfl_xor(m, off));
    float e0 = __expf(v0 - m), e1 = __expf(v1 - m);
    float sum = e0 + e1;
#pragma unroll
    for (int off = 32; off; off >>= 1) sum += __shfl_xor(sum, off);
    float r = 1.0f / sum;
    float* ab = at + (size_t)blk * 128;
    ab[t0] = e0 * r; ab[t1] = e1 * r;
}

__global__ __launch_bounds__(64) void k_softmax_ta(
    float* __restrict__ mul, const int* __restrict__ ssent,
    const int* __restrict__ tsent)
{
    int blk = blockIdx.x;
    int b = blk >> 7, t = blk & 127;
    int lane = threadIdx.x;
    bool tm = tsent[b * 128 + t] > 0;
    float* mb = mul + (size_t)blk * 128;
    int s0 = lane, s1 = lane + 64;
    float v0 = (tm && ssent[b * 128 + s0] > 0) ? mb[s0] : NEG_INF;
    float v1 = (tm && ssent[b * 128 + s1] > 0) ? mb[s1] : NEG_INF;
    float m = fmaxf(v0, v1);
#pragma unroll
    for (int off = 32; off; off >>= 1) m = fmaxf(m, __shfl_xor(m, off));
    float e0 = __expf(v0 - m), e1 = __expf(v1 - m);
    float sum = e0 + e1;
#pragma unroll
    for (int off = 32; off; off >>= 1) sum += __shfl_xor(sum, off);
    float r = 1.0f / sum;
    mb[s0] = e0 * r; mb[s1] = e1 * r;
}

__global__ __launch_bounds__(256) void k_attmm(
    const float* __restrict__ P, const float* __restrict__ E,
    float* __restrict__ C)
{
    __shared__ float Pt[32][68];
    __shared__ float Et[32][68];
    int b = blockIdx.y;
    int r0 = (blockIdx.x >> 4) * 64, d0 = (blockIdx.x & 15) * 64;
    const float* Pb = P + (size_t)b * 16384;
    const float* Eb = E + (size_t)b * 131072;
    float* Cb = C + (size_t)b * 131072;
    int tid = threadIdx.x, ty = tid >> 4, tx = tid & 15;
    float acc[4][4] = {};
    for (int k0 = 0; k0 < 128; k0 += 32) {
        for (int q = tid; q < 512; q += 256) {
            int r = q >> 3, kc = (q & 7) << 2;
            float4 v = *(const float4*)(Pb + (size_t)(r0 + r) * 128 + k0 + kc);
            Pt[kc+0][r] = v.x; Pt[kc+1][r] = v.y; Pt[kc+2][r] = v.z; Pt[kc+3][r] = v.w;
            int kr = q >> 4, dc = (q & 15) << 2;
            *(float4*)&Et[kr][dc] = *(const float4*)(Eb + (size_t)(k0 + kr) * 1024 + d0 + dc);
        }
        __syncthreads();
#pragma unroll 8
        for (int kk = 0; kk < 32; ++kk) {
            float4 av = *(const float4*)&Pt[kk][ty << 2];
            float4 bv = *(const float4*)&Et[kk][tx << 2];
            float aa[4] = {av.x, av.y, av.z, av.w};
            float bb[4] = {bv.x, bv.y, bv.z, bv.w};
#pragma unroll
            for (int i = 0; i < 4; ++i)
#pragma unroll
                for (int j = 0; j < 4; ++j)
                    acc[i][j] = fmaf(aa[i], bb[j], acc[i][j]);
        }
        __syncthreads();
    }
#pragma unroll
    for (int i = 0; i < 4; ++i)
        *(float4*)(Cb + (size_t)(r0 + (ty << 2) + i) * 1024 + d0 + (tx << 2)) =
            make_float4(acc[i][0], acc[i][1], acc[i][2], acc[i][3]);
}

// ---------------------------------------------------------------------------
extern "C" void kernel_launch(void* const* d_in, const int* in_sizes, int n_in,
                              void* d_out, int out_size, void* d_ws, size_t ws_size,
                              hipStream_t stream)
{
    const int*   ssent = (const int*)d_in[0];
    const int*   tsent = (const int*)d_in[1];
    const float* stab  = (const float*)d_in[4];
    const float* ttab  = (const float*)d_in[5];
    float* out  = (float*)d_out;

    float* src  = out + 0;
    float* satt = out + 8388608;
    float* at   = out + 16777216;
    float* tgt  = out + 17825792;
    float* tatt = out + 26214400;
    float* ta   = out + 34603008;

    const size_t EB_ELEMS = 8388608;     // 64*128*1024
    const size_t P_ELEMS  = 1048576;     // 64*128*128
    const size_t WS_NEED  = (4 * EB_ELEMS + 2 * P_ELEMS) * sizeof(ushort)
                          + P_ELEMS * sizeof(float);   // ~75.5 MB

    if (ws_size >= WS_NEED) {
        ushort* ebS  = (ushort*)d_ws;
        ushort* ebT  = ebS  + EB_ELEMS;
        ushort* ebtS = ebT  + EB_ELEMS;
        ushort* ebtT = ebtS + EB_ELEMS;
        ushort* pta  = ebtT + EB_ELEMS;
        ushort* pat  = pta  + P_ELEMS;
        float*  mulraw = (float*)(pat + P_ELEMS);

        k_embed_all2<<<1024, 256, 0, stream>>>(ssent, tsent, stab, ttab,
                                               src, tgt, ebS, ebT, ebtS, ebtT);
        k_scores_splitk<<<1024, 256, 0, stream>>>(ebS, ebT, mulraw);
        k_softmax_dual<<<8192, 64, 0, stream>>>(mulraw, ssent, tsent,
                                                at, ta, pat, pta);
        k_attmm2<<<8192, 64, 0, stream>>>(pta, ebtS, satt, pat, ebtT, tatt);
    } else {
        // fp32 fallback
        k_embed_pool<<<8192, 256, 0, stream>>>(ssent, stab, src);
        k_embed_pool<<<8192, 256, 0, stream>>>(tsent, ttab, tgt);
        k_scores<<<dim3(4, 64), 256, 0, stream>>>(src, tgt, ta);
        k_softmax_at<<<8192, 64, 0, stream>>>(ta, ssent, tsent, at);
        k_softmax_ta<<<8192, 64, 0, stream>>>(ta, ssent, tsent);
        k_attmm<<<dim3(32, 64), 256, 0, stream>>>(ta, src, satt);
        k_attmm<<<dim3(32, 64), 256, 0, stream>>>(at, tgt, tatt);
    }
}